// Round 20
// baseline (59.910 us; speedup 1.0000x reference)
//
#include <hip/hip_runtime.h>
#include <hip/hip_bf16.h>

#define B_ 4
#define T_ 64
#define N_ 325
#define NP 336                  // padded graph dim for MFMA
#define F_ 3
#define DH 16
#define DD 64
#define NH 4
#define BT_ 256                 // B*T
#define M_ 4096                 // BT*DH

using f16x4 = __attribute__((ext_vector_type(4))) _Float16;
using f32x4 = __attribute__((ext_vector_type(4))) float;
#define MFMA16 __builtin_amdgcn_mfma_f32_16x16x16f16

// ---------------- K1: fused {support-MFMA | lintrans} by block range ---------
// lintrans: 8 elems/thread -> 650 blocks; total grid 776.
__global__ __launch_bounds__(256) void k_prep(const float* __restrict__ adj,
                                              const float* __restrict__ in,
                                              const float* __restrict__ w,
                                              const float* __restrict__ bias,
                                              _Float16* __restrict__ S16,
                                              _Float16* __restrict__ X16) {
    int tid = threadIdx.x;
    if (blockIdx.x < 126) {
        __shared__ __align__(16) float red[4][16][68];
        int sb = blockIdx.x;
        int j0 = (sb % 6) * 64;
        int i0 = (sb / 6) * 16;
        int w4 = tid >> 6, l = tid & 63;
        int lr = l & 15, kg = l >> 4;
        int c0 = w4 * 5;
        int nc = (w4 == 3) ? 6 : 5;    // 21 K-chunks of 16 over NP=336

        f32x4 acc0 = {0.f,0.f,0.f,0.f}, acc1 = acc0, acc2 = acc0, acc3 = acc0;
        int I = i0 + lr;
        for (int cc = 0; cc < nc; ++cc) {
            int kb = (c0 + cc) * 16 + kg * 4;
            f16x4 af, b0, b1, b2, b3;
#pragma unroll
            for (int j = 0; j < 4; ++j) {
                int k = kb + j;
                af[j] = (I < N_ && k < N_) ? (_Float16)adj[I * N_ + k] : (_Float16)0.f;
                _Float16 x0 = (_Float16)0.f, x1 = x0, x2 = x0, x3 = x0;
                if (k < N_) {
                    const float* ar = adj + (size_t)k * N_;
                    int m0 = j0 + lr;
                    if (m0 < N_)      x0 = (_Float16)ar[m0];
                    if (m0 + 16 < N_) x1 = (_Float16)ar[m0 + 16];
                    if (m0 + 32 < N_) x2 = (_Float16)ar[m0 + 32];
                    if (m0 + 48 < N_) x3 = (_Float16)ar[m0 + 48];
                }
                b0[j] = x0; b1[j] = x1; b2[j] = x2; b3[j] = x3;
            }
            acc0 = MFMA16(af, b0, acc0, 0, 0, 0);
            acc1 = MFMA16(af, b1, acc1, 0, 0, 0);
            acc2 = MFMA16(af, b2, acc2, 0, 0, 0);
            acc3 = MFMA16(af, b3, acc3, 0, 0, 0);
        }
#pragma unroll
        for (int r = 0; r < 4; ++r) {
            red[w4][kg * 4 + r][ 0 + lr] = acc0[r];
            red[w4][kg * 4 + r][16 + lr] = acc1[r];
            red[w4][kg * 4 + r][32 + lr] = acc2[r];
            red[w4][kg * 4 + r][48 + lr] = acc3[r];
        }
        __syncthreads();
        int row = tid >> 4, col = (tid & 15) * 4;
        int I2 = i0 + row;
#pragma unroll
        for (int q = 0; q < 4; ++q) {
            int J = j0 + col + q;
            if (J < NP) {
                float v = 0.f;
                if (I2 < N_ && J < N_) {
                    float r4 = ((red[0][row][col + q] + red[1][row][col + q]) +
                                (red[2][row][col + q] + red[3][row][col + q]));
                    v = adj[I2 * N_ + J] + 2.f * r4;
                }
                S16[I2 * NP + J] = (_Float16)v;
            }
        }
    } else {
        int idx8 = ((blockIdx.x - 126) * 256 + tid) * 8;   // 8 elems/thread
        if (idx8 >= N_ * M_) return;
        int n = idx8 >> 12;
        int r = idx8 & 4095;
        int bt = r >> 4, c0 = r & 15;     // c0 in {0, 8}
        int tok = bt * N_ + n;
        float f0 = in[tok * 3 + 0];
        float f1 = in[tok * 3 + 1];
        float f2 = in[tok * 3 + 2];
        f16x4 o0, o1;
#pragma unroll
        for (int j = 0; j < 4; ++j) {
            int c = c0 + j;
            o0[j] = (_Float16)fmaxf(bias[c] + f0*w[c*3+0] + f1*w[c*3+1] + f2*w[c*3+2], 0.f);
        }
#pragma unroll
        for (int j = 0; j < 4; ++j) {
            int c = c0 + 4 + j;
            o1[j] = (_Float16)fmaxf(bias[c] + f0*w[c*3+0] + f1*w[c*3+1] + f2*w[c*3+2], 0.f);
        }
        *(f16x4*)&X16[idx8] = o0;
        *(f16x4*)&X16[idx8 + 4] = o1;
    }
}

// ---------------- K2: lfs16 = f16(S @ X) — 4 m-tiles/block, shared A-frag ----
__global__ __launch_bounds__(256) void k_gconv(const _Float16* __restrict__ S16,
                                               const _Float16* __restrict__ X16,
                                               _Float16* __restrict__ lfs16) {
    __shared__ __align__(16) float red[4][16][68];
    int mb0 = blockIdx.x * 256;           // four 64-wide m-tiles
    int i0 = blockIdx.y * 16;
    int tid = threadIdx.x;
    int w = tid >> 6, l = tid & 63;
    int lr = l & 15, kg = l >> 4;

    int c0 = w * 5;
    int nc = (w == 3) ? 6 : 5;    // 21 chunks of K=16 total (336 = NP)
    const size_t arow = (size_t)(i0 + lr) * NP;

#pragma unroll
    for (int half = 0; half < 4; ++half) {
        int m0 = mb0 + half * 64;
        f32x4 acc0 = {0.f,0.f,0.f,0.f}, acc1 = acc0, acc2 = acc0, acc3 = acc0;
        for (int cc = 0; cc < nc; ++cc) {
            int kb = (c0 + cc) * 16 + kg * 4;
            f16x4 af = *(const f16x4*)&S16[arow + kb];   // pads zeroed; L1-hot after half 0
            f16x4 b0, b1, b2, b3;
#pragma unroll
            for (int j = 0; j < 4; ++j) {
                int k = kb + j;
                _Float16 x0 = (_Float16)0.f, x1 = x0, x2 = x0, x3 = x0;
                if (k < N_) {
                    const _Float16* xr = X16 + (size_t)k * M_ + m0;
                    x0 = xr[lr]; x1 = xr[16 + lr]; x2 = xr[32 + lr]; x3 = xr[48 + lr];
                }
                b0[j] = x0; b1[j] = x1; b2[j] = x2; b3[j] = x3;
            }
            acc0 = MFMA16(af, b0, acc0, 0, 0, 0);
            acc1 = MFMA16(af, b1, acc1, 0, 0, 0);
            acc2 = MFMA16(af, b2, acc2, 0, 0, 0);
            acc3 = MFMA16(af, b3, acc3, 0, 0, 0);
        }
        if (half) __syncthreads();        // protect red reuse
#pragma unroll
        for (int r = 0; r < 4; ++r) {
            red[w][kg * 4 + r][ 0 + lr] = acc0[r];
            red[w][kg * 4 + r][16 + lr] = acc1[r];
            red[w][kg * 4 + r][32 + lr] = acc2[r];
            red[w][kg * 4 + r][48 + lr] = acc3[r];
        }
        __syncthreads();
        int row = tid >> 4, col = (tid & 15) * 4;
        if (i0 + row < N_) {
            float4 p0 = *(const float4*)&red[0][row][col];
            float4 p1 = *(const float4*)&red[1][row][col];
            float4 p2 = *(const float4*)&red[2][row][col];
            float4 p3 = *(const float4*)&red[3][row][col];
            f16x4 o;
            o[0] = (_Float16)((p0.x + p1.x) + (p2.x + p3.x));
            o[1] = (_Float16)((p0.y + p1.y) + (p2.y + p3.y));
            o[2] = (_Float16)((p0.z + p1.z) + (p2.z + p3.z));
            o[3] = (_Float16)((p0.w + p1.w) + (p2.w + p3.w));
            *(f16x4*)&lfs16[(size_t)(i0 + row) * M_ + m0 + col] = o;
        }
    }
}

// ---------------- K3: MFMA attention — residual from X16 (contiguous) --------
__global__ __launch_bounds__(256) void k_attn(
    const _Float16* __restrict__ lfs16, const _Float16* __restrict__ X16,
    const float* __restrict__ wq, const float* __restrict__ bq,
    const float* __restrict__ wk, const float* __restrict__ bk,
    const float* __restrict__ wv, const float* __restrict__ bv,
    const float* __restrict__ wls, const float* __restrict__ bls,
    _Float16* __restrict__ ypre16, float* __restrict__ part) {
    __shared__ __align__(16) float Rs[NH][T_][20];
    __shared__ float lnp[NH][2];
    int bn = blockIdx.x;
    int b = bn / N_, n = bn % N_;
    int tid = threadIdx.x;
    int h = tid >> 6;
    int l = tid & 63;
    int lr = l & 15, kg = l >> 4;

    const _Float16* Lsrc = lfs16 + (size_t)n * M_ + b * (T_ * DH);
    f16x4 lff[4];
#pragma unroll
    for (int q = 0; q < 4; ++q)
        lff[q] = *(const f16x4*)&Lsrc[(lr + 16 * q) * DH + kg * 4];

    f16x4 wqf, wkf, wvf, wlf;
    {
        int base = h * 16 + lr;
#pragma unroll
        for (int j = 0; j < 4; ++j) {
            wqf[j] = (_Float16)wq[(kg * 4 + j) * DD + base];
            wkf[j] = (_Float16)wk[(kg * 4 + j) * DD + base];
            wvf[j] = (_Float16)wv[(kg * 4 + j) * DD + base];
        }
        const float4 w4 = *(const float4*)&wls[lr * DD + h * 16 + kg * 4];
        wlf[0] = (_Float16)w4.x; wlf[1] = (_Float16)w4.y; wlf[2] = (_Float16)w4.z; wlf[3] = (_Float16)w4.w;
    }
    f32x4 zero = {0.f, 0.f, 0.f, 0.f};

    f16x4 qtf[4], ktf[4], vvf[4];
    {
        float bqr[4], bkr[4];
#pragma unroll
        for (int r = 0; r < 4; ++r) { bqr[r] = bq[h * 16 + kg * 4 + r]; bkr[r] = bk[h * 16 + kg * 4 + r]; }
        float bvc = bv[h * 16 + lr];
#pragma unroll
        for (int q = 0; q < 4; ++q) {
            f32x4 qa = MFMA16(wqf, lff[q], zero, 0, 0, 0);
            f32x4 ka = MFMA16(wkf, lff[q], zero, 0, 0, 0);
            f32x4 va = MFMA16(lff[q], wvf, zero, 0, 0, 0);
#pragma unroll
            for (int r = 0; r < 4; ++r) {
                qtf[q][r] = (_Float16)(fmaxf(qa[r] + bqr[r], 0.f) * 0.25f);
                ktf[q][r] = (_Float16)fmaxf(ka[r] + bkr[r], 0.f);
                vvf[q][r] = (_Float16)fmaxf(va[r] + bvc, 0.f);
            }
        }
    }

#pragma unroll
    for (int tt = 0; tt < 4; ++tt) {
        f32x4 stc[4];
#pragma unroll
        for (int ss = 0; ss < 4; ++ss)
            stc[ss] = MFMA16(ktf[ss], qtf[tt], zero, 0, 0, 0);
        int t = tt * 16 + lr;
        float m = -1e30f;
#pragma unroll
        for (int ss = 0; ss < 4; ++ss)
#pragma unroll
            for (int r = 0; r < 4; ++r) m = fmaxf(m, stc[ss][r]);
        m = fmaxf(m, __shfl_xor(m, 16));
        m = fmaxf(m, __shfl_xor(m, 32));
        float e[4][4];
        float sum = 0.f;
#pragma unroll
        for (int ss = 0; ss < 4; ++ss)
#pragma unroll
            for (int r = 0; r < 4; ++r) { float ev = __expf(stc[ss][r] - m); e[ss][r] = ev; sum += ev; }
        sum += __shfl_xor(sum, 16);
        sum += __shfl_xor(sum, 32);
        float inv = 1.f / sum;
        f16x4 pc[4];
#pragma unroll
        for (int ss = 0; ss < 4; ++ss)
#pragma unroll
            for (int r = 0; r < 4; ++r) {
                int s = ss * 16 + kg * 4 + r;
                pc[ss][r] = (s <= t) ? (_Float16)(e[ss][r] * inv) : (_Float16)0.f;
            }
        f32x4 acc = zero;
#pragma unroll
        for (int ss = 0; ss < 4; ++ss)
            acc = MFMA16(vvf[ss], pc[ss], acc, 0, 0, 0);
        f16x4 rt;
#pragma unroll
        for (int r = 0; r < 4; ++r) rt[r] = (_Float16)fmaxf(acc[r], 0.f);
        f32x4 rp = MFMA16(wlf, rt, zero, 0, 0, 0);
        float4 o4; o4.x = rp[0]; o4.y = rp[1]; o4.z = rp[2]; o4.w = rp[3];
        *(float4*)&Rs[h][t][kg * 4] = o4;
    }
    __syncthreads();

    {
        int t = tid >> 2, o0 = (tid & 3) * 4;
        float4 r0 = *(const float4*)&Rs[0][t][o0];
        float4 r1 = *(const float4*)&Rs[1][t][o0];
        float4 r2 = *(const float4*)&Rs[2][t][o0];
        float4 r3 = *(const float4*)&Rs[3][t][o0];
        // residual from X16 (same rounded X the gconv consumed) — contiguous
        f16x4 xv = *(const f16x4*)&X16[(size_t)n * M_ + b * (T_ * DH) + t * DH + o0];
        float y0 = (float)xv[0] + fmaxf(r0.x + r1.x + r2.x + r3.x + bls[o0 + 0], 0.f);
        float y1 = (float)xv[1] + fmaxf(r0.y + r1.y + r2.y + r3.y + bls[o0 + 1], 0.f);
        float y2 = (float)xv[2] + fmaxf(r0.z + r1.z + r2.z + r3.z + bls[o0 + 2], 0.f);
        float y3 = (float)xv[3] + fmaxf(r0.w + r1.w + r2.w + r3.w + bls[o0 + 3], 0.f);
        f16x4 yv16;
        yv16[0] = (_Float16)y0; yv16[1] = (_Float16)y1;
        yv16[2] = (_Float16)y2; yv16[3] = (_Float16)y3;
        // OUTPUT-order store: [b][t][n][c]
        *(f16x4*)&ypre16[(((size_t)(b * T_ + t) * N_) + n) * DH + o0] = yv16;
        float ls = (y0 + y1) + (y2 + y3);
        float lq = (y0 * y0 + y1 * y1) + (y2 * y2 + y3 * y3);
#pragma unroll
        for (int off = 32; off > 0; off >>= 1) { ls += __shfl_down(ls, off); lq += __shfl_down(lq, off); }
        if (l == 0) { lnp[h][0] = ls; lnp[h][1] = lq; }
    }
    __syncthreads();
    if (tid == 0) {
        part[bn * 2]     = (lnp[0][0] + lnp[1][0]) + (lnp[2][0] + lnp[3][0]);
        part[bn * 2 + 1] = (lnp[0][1] + lnp[1][1]) + (lnp[2][1] + lnp[3][1]);
    }
}

// ---------------- K4: LN stats + normalize, block=(b,t) ----------------------
__global__ __launch_bounds__(256) void k_lnapply(const _Float16* __restrict__ y16,
                                                 const float* __restrict__ part,
                                                 const float* __restrict__ gamma,
                                                 const float* __restrict__ beta,
                                                 float* __restrict__ out) {
    __shared__ float gs[N_ * DH];    // 20.8 KB, layout [c][n]
    __shared__ float bsh[N_ * DH];   // 20.8 KB
    __shared__ float ssum[256], ssq[256];
    int blk = blockIdx.x, tid = threadIdx.x;
    int b = blk >> 6, t = blk & 63;
    for (int i = tid; i < N_ * DH; i += 256) {      // i = c*325+n: contiguous runs
        int c = i / N_, n = i - c * N_;
        size_t g = (size_t)(c * T_ + t) * N_ + n;
        gs[i] = gamma[g];
        bsh[i] = beta[g];
    }
    float s = 0.f, q = 0.f;
    for (int i = tid; i < N_; i += 256) {
        s += part[(b * N_ + i) * 2];
        q += part[(b * N_ + i) * 2 + 1];
    }
    ssum[tid] = s; ssq[tid] = q;
    __syncthreads();
    for (int st = 128; st > 0; st >>= 1) {
        if (tid < st) { ssum[tid] += ssum[tid + st]; ssq[tid] += ssq[tid + st]; }
        __syncthreads();
    }
    float mu = ssum[0] / 332800.f;
    float rs = rsqrtf(ssq[0] / 332800.f - mu * mu + 1e-5f);

    float* ob = out + (size_t)(b * T_ + t) * (N_ * DH);
    const _Float16* yb = y16 + (size_t)(b * T_ + t) * (N_ * DH);
    for (int e4 = tid; e4 < (N_ * DH) / 4; e4 += 256) {   // contiguous f16x4 / float4
        f16x4 yv = *(const f16x4*)&yb[e4 * 4];
        int e = e4 * 4;
        int n = e >> 4, c0 = e & 15;
        float4 o;
        o.x = ((float)yv[0] - mu) * rs * gs[(c0 + 0) * N_ + n] + bsh[(c0 + 0) * N_ + n];
        o.y = ((float)yv[1] - mu) * rs * gs[(c0 + 1) * N_ + n] + bsh[(c0 + 1) * N_ + n];
        o.z = ((float)yv[2] - mu) * rs * gs[(c0 + 2) * N_ + n] + bsh[(c0 + 2) * N_ + n];
        o.w = ((float)yv[3] - mu) * rs * gs[(c0 + 3) * N_ + n] + bsh[(c0 + 3) * N_ + n];
        *(float4*)&ob[e] = o;
    }
}

extern "C" void kernel_launch(void* const* d_in, const int* in_sizes, int n_in,
                              void* d_out, int out_size, void* d_ws, size_t ws_size,
                              hipStream_t stream) {
    const float* in   = (const float*)d_in[0];
    const float* adj  = (const float*)d_in[1];
    const float* w_lt = (const float*)d_in[2];
    const float* b_lt = (const float*)d_in[3];
    const float* wq   = (const float*)d_in[4];
    const float* bq   = (const float*)d_in[5];
    const float* wk   = (const float*)d_in[6];
    const float* bk   = (const float*)d_in[7];
    const float* wv   = (const float*)d_in[8];
    const float* bv   = (const float*)d_in[9];
    const float* wls  = (const float*)d_in[10];
    const float* bls  = (const float*)d_in[11];
    const float* gam  = (const float*)d_in[12];
    const float* bet  = (const float*)d_in[13];
    float* out = (float*)d_out;

    float* ws = (float*)d_ws;
    _Float16* S16    = (_Float16*)ws;                              // NP*NP f16
    _Float16* X16    = (_Float16*)(ws + 56576);                    // 1,331,200 f16
    _Float16* lfs16  = (_Float16*)(ws + 56576 + 665600);           // 1,331,200 f16
    _Float16* ypre16 = (_Float16*)(ws + 56576 + 665600 + 665600);  // 1,331,200 f16 [b][t][n][c]
    float* part = ws + 56576 + 665600 + 665600 + 665600;           // 2600

    k_prep<<<126 + 650, 256, 0, stream>>>(adj, in, w_lt, b_lt, S16, X16);
    k_gconv<<<dim3(16, 21), 256, 0, stream>>>(S16, X16, lfs16);
    k_attn<<<B_ * N_, 256, 0, stream>>>(lfs16, X16, wq, bq, wk, bk, wv, bv, wls, bls, ypre16, part);
    k_lnapply<<<B_ * T_, 256, 0, stream>>>(ypre16, part, gam, bet, out);
}

// Round 21
// 54.186 us; speedup vs baseline: 1.1056x; 1.1056x over previous
//
#include <hip/hip_runtime.h>
#include <hip/hip_bf16.h>

#define B_ 4
#define T_ 64
#define N_ 325
#define NP 336                  // padded graph dim for MFMA
#define F_ 3
#define DH 16
#define DD 64
#define NH 4
#define BT_ 256                 // B*T
#define M_ 4096                 // BT*DH

using f16x4 = __attribute__((ext_vector_type(4))) _Float16;
using f32x4 = __attribute__((ext_vector_type(4))) float;
#define MFMA16 __builtin_amdgcn_mfma_f32_16x16x16f16

// ---------------- K1: fused {support-MFMA | lintrans} by block range ---------
__global__ __launch_bounds__(256) void k_prep(const float* __restrict__ adj,
                                              const float* __restrict__ in,
                                              const float* __restrict__ w,
                                              const float* __restrict__ bias,
                                              _Float16* __restrict__ S16,
                                              _Float16* __restrict__ X16) {
    int tid = threadIdx.x;
    if (blockIdx.x < 126) {
        __shared__ __align__(16) float red[4][16][68];
        int sb = blockIdx.x;
        int j0 = (sb % 6) * 64;
        int i0 = (sb / 6) * 16;
        int w4 = tid >> 6, l = tid & 63;
        int lr = l & 15, kg = l >> 4;
        int c0 = w4 * 5;
        int nc = (w4 == 3) ? 6 : 5;    // 21 K-chunks of 16 over NP=336

        f32x4 acc0 = {0.f,0.f,0.f,0.f}, acc1 = acc0, acc2 = acc0, acc3 = acc0;
        int I = i0 + lr;
        for (int cc = 0; cc < nc; ++cc) {
            int kb = (c0 + cc) * 16 + kg * 4;
            f16x4 af, b0, b1, b2, b3;
#pragma unroll
            for (int j = 0; j < 4; ++j) {
                int k = kb + j;
                af[j] = (I < N_ && k < N_) ? (_Float16)adj[I * N_ + k] : (_Float16)0.f;
                _Float16 x0 = (_Float16)0.f, x1 = x0, x2 = x0, x3 = x0;
                if (k < N_) {
                    const float* ar = adj + (size_t)k * N_;
                    int m0 = j0 + lr;
                    if (m0 < N_)      x0 = (_Float16)ar[m0];
                    if (m0 + 16 < N_) x1 = (_Float16)ar[m0 + 16];
                    if (m0 + 32 < N_) x2 = (_Float16)ar[m0 + 32];
                    if (m0 + 48 < N_) x3 = (_Float16)ar[m0 + 48];
                }
                b0[j] = x0; b1[j] = x1; b2[j] = x2; b3[j] = x3;
            }
            acc0 = MFMA16(af, b0, acc0, 0, 0, 0);
            acc1 = MFMA16(af, b1, acc1, 0, 0, 0);
            acc2 = MFMA16(af, b2, acc2, 0, 0, 0);
            acc3 = MFMA16(af, b3, acc3, 0, 0, 0);
        }
#pragma unroll
        for (int r = 0; r < 4; ++r) {
            red[w4][kg * 4 + r][ 0 + lr] = acc0[r];
            red[w4][kg * 4 + r][16 + lr] = acc1[r];
            red[w4][kg * 4 + r][32 + lr] = acc2[r];
            red[w4][kg * 4 + r][48 + lr] = acc3[r];
        }
        __syncthreads();
        int row = tid >> 4, col = (tid & 15) * 4;
        int I2 = i0 + row;
#pragma unroll
        for (int q = 0; q < 4; ++q) {
            int J = j0 + col + q;
            if (J < NP) {
                float v = 0.f;
                if (I2 < N_ && J < N_) {
                    float r4 = ((red[0][row][col + q] + red[1][row][col + q]) +
                                (red[2][row][col + q] + red[3][row][col + q]));
                    v = adj[I2 * N_ + J] + 2.f * r4;
                }
                S16[I2 * NP + J] = (_Float16)v;
            }
        }
    } else {
        int idx4 = ((blockIdx.x - 126) * 256 + tid) * 4;
        if (idx4 >= N_ * M_) return;
        int n = idx4 >> 12;
        int r = idx4 & 4095;
        int bt = r >> 4, c0 = r & 15;
        int tok = bt * N_ + n;
        float f0 = in[tok * 3 + 0];
        float f1 = in[tok * 3 + 1];
        float f2 = in[tok * 3 + 2];
        f16x4 o;
        o[0] = (_Float16)fmaxf(bias[c0+0] + f0*w[(c0+0)*3+0] + f1*w[(c0+0)*3+1] + f2*w[(c0+0)*3+2], 0.f);
        o[1] = (_Float16)fmaxf(bias[c0+1] + f0*w[(c0+1)*3+0] + f1*w[(c0+1)*3+1] + f2*w[(c0+1)*3+2], 0.f);
        o[2] = (_Float16)fmaxf(bias[c0+2] + f0*w[(c0+2)*3+0] + f1*w[(c0+2)*3+1] + f2*w[(c0+2)*3+2], 0.f);
        o[3] = (_Float16)fmaxf(bias[c0+3] + f0*w[(c0+3)*3+0] + f1*w[(c0+3)*3+1] + f2*w[(c0+3)*3+2], 0.f);
        *(f16x4*)&X16[idx4] = o;
    }
}

// ---------------- K2: lfs16 = f16(S @ X) — 2 m-tiles/block, shared A-frag ----
__global__ __launch_bounds__(256) void k_gconv(const _Float16* __restrict__ S16,
                                               const _Float16* __restrict__ X16,
                                               _Float16* __restrict__ lfs16) {
    __shared__ __align__(16) float red[4][16][68];
    int mb0 = blockIdx.x * 128;           // two 64-wide m-tiles
    int i0 = blockIdx.y * 16;
    int tid = threadIdx.x;
    int w = tid >> 6, l = tid & 63;
    int lr = l & 15, kg = l >> 4;

    int c0 = w * 5;
    int nc = (w == 3) ? 6 : 5;    // 21 chunks of K=16 total (336 = NP)
    const size_t arow = (size_t)(i0 + lr) * NP;

#pragma unroll
    for (int half = 0; half < 2; ++half) {
        int m0 = mb0 + half * 64;
        f32x4 acc0 = {0.f,0.f,0.f,0.f}, acc1 = acc0, acc2 = acc0, acc3 = acc0;
        for (int cc = 0; cc < nc; ++cc) {
            int kb = (c0 + cc) * 16 + kg * 4;
            f16x4 af = *(const f16x4*)&S16[arow + kb];   // pads zeroed; L2-hot on half=1
            f16x4 b0, b1, b2, b3;
#pragma unroll
            for (int j = 0; j < 4; ++j) {
                int k = kb + j;
                _Float16 x0 = (_Float16)0.f, x1 = x0, x2 = x0, x3 = x0;
                if (k < N_) {
                    const _Float16* xr = X16 + (size_t)k * M_ + m0;
                    x0 = xr[lr]; x1 = xr[16 + lr]; x2 = xr[32 + lr]; x3 = xr[48 + lr];
                }
                b0[j] = x0; b1[j] = x1; b2[j] = x2; b3[j] = x3;
            }
            acc0 = MFMA16(af, b0, acc0, 0, 0, 0);
            acc1 = MFMA16(af, b1, acc1, 0, 0, 0);
            acc2 = MFMA16(af, b2, acc2, 0, 0, 0);
            acc3 = MFMA16(af, b3, acc3, 0, 0, 0);
        }
        if (half) __syncthreads();        // protect red reuse
#pragma unroll
        for (int r = 0; r < 4; ++r) {
            red[w][kg * 4 + r][ 0 + lr] = acc0[r];
            red[w][kg * 4 + r][16 + lr] = acc1[r];
            red[w][kg * 4 + r][32 + lr] = acc2[r];
            red[w][kg * 4 + r][48 + lr] = acc3[r];
        }
        __syncthreads();
        int row = tid >> 4, col = (tid & 15) * 4;
        if (i0 + row < N_) {
            float4 p0 = *(const float4*)&red[0][row][col];
            float4 p1 = *(const float4*)&red[1][row][col];
            float4 p2 = *(const float4*)&red[2][row][col];
            float4 p3 = *(const float4*)&red[3][row][col];
            f16x4 o;
            o[0] = (_Float16)((p0.x + p1.x) + (p2.x + p3.x));
            o[1] = (_Float16)((p0.y + p1.y) + (p2.y + p3.y));
            o[2] = (_Float16)((p0.z + p1.z) + (p2.z + p3.z));
            o[3] = (_Float16)((p0.w + p1.w) + (p2.w + p3.w));
            *(f16x4*)&lfs16[(size_t)(i0 + row) * M_ + m0 + col] = o;
        }
    }
}

// ---------------- K3: MFMA attention — residual from X16 (contiguous) --------
__global__ __launch_bounds__(256) void k_attn(
    const _Float16* __restrict__ lfs16, const _Float16* __restrict__ X16,
    const float* __restrict__ wq, const float* __restrict__ bq,
    const float* __restrict__ wk, const float* __restrict__ bk,
    const float* __restrict__ wv, const float* __restrict__ bv,
    const float* __restrict__ wls, const float* __restrict__ bls,
    _Float16* __restrict__ ypre16, float* __restrict__ part) {
    __shared__ __align__(16) float Rs[NH][T_][20];
    __shared__ float lnp[NH][2];
    int bn = blockIdx.x;
    int b = bn / N_, n = bn % N_;
    int tid = threadIdx.x;
    int h = tid >> 6;
    int l = tid & 63;
    int lr = l & 15, kg = l >> 4;

    const _Float16* Lsrc = lfs16 + (size_t)n * M_ + b * (T_ * DH);
    f16x4 lff[4];
#pragma unroll
    for (int q = 0; q < 4; ++q)
        lff[q] = *(const f16x4*)&Lsrc[(lr + 16 * q) * DH + kg * 4];

    f16x4 wqf, wkf, wvf, wlf;
    {
        int base = h * 16 + lr;
#pragma unroll
        for (int j = 0; j < 4; ++j) {
            wqf[j] = (_Float16)wq[(kg * 4 + j) * DD + base];
            wkf[j] = (_Float16)wk[(kg * 4 + j) * DD + base];
            wvf[j] = (_Float16)wv[(kg * 4 + j) * DD + base];
        }
        const float4 w4 = *(const float4*)&wls[lr * DD + h * 16 + kg * 4];
        wlf[0] = (_Float16)w4.x; wlf[1] = (_Float16)w4.y; wlf[2] = (_Float16)w4.z; wlf[3] = (_Float16)w4.w;
    }
    f32x4 zero = {0.f, 0.f, 0.f, 0.f};

    f16x4 qtf[4], ktf[4], vvf[4];
    {
        float bqr[4], bkr[4];
#pragma unroll
        for (int r = 0; r < 4; ++r) { bqr[r] = bq[h * 16 + kg * 4 + r]; bkr[r] = bk[h * 16 + kg * 4 + r]; }
        float bvc = bv[h * 16 + lr];
#pragma unroll
        for (int q = 0; q < 4; ++q) {
            f32x4 qa = MFMA16(wqf, lff[q], zero, 0, 0, 0);
            f32x4 ka = MFMA16(wkf, lff[q], zero, 0, 0, 0);
            f32x4 va = MFMA16(lff[q], wvf, zero, 0, 0, 0);
#pragma unroll
            for (int r = 0; r < 4; ++r) {
                qtf[q][r] = (_Float16)(fmaxf(qa[r] + bqr[r], 0.f) * 0.25f);
                ktf[q][r] = (_Float16)fmaxf(ka[r] + bkr[r], 0.f);
                vvf[q][r] = (_Float16)fmaxf(va[r] + bvc, 0.f);
            }
        }
    }

#pragma unroll
    for (int tt = 0; tt < 4; ++tt) {
        f32x4 stc[4];
#pragma unroll
        for (int ss = 0; ss < 4; ++ss)
            stc[ss] = MFMA16(ktf[ss], qtf[tt], zero, 0, 0, 0);
        int t = tt * 16 + lr;
        float m = -1e30f;
#pragma unroll
        for (int ss = 0; ss < 4; ++ss)
#pragma unroll
            for (int r = 0; r < 4; ++r) m = fmaxf(m, stc[ss][r]);
        m = fmaxf(m, __shfl_xor(m, 16));
        m = fmaxf(m, __shfl_xor(m, 32));
        float e[4][4];
        float sum = 0.f;
#pragma unroll
        for (int ss = 0; ss < 4; ++ss)
#pragma unroll
            for (int r = 0; r < 4; ++r) { float ev = __expf(stc[ss][r] - m); e[ss][r] = ev; sum += ev; }
        sum += __shfl_xor(sum, 16);
        sum += __shfl_xor(sum, 32);
        float inv = 1.f / sum;
        f16x4 pc[4];
#pragma unroll
        for (int ss = 0; ss < 4; ++ss)
#pragma unroll
            for (int r = 0; r < 4; ++r) {
                int s = ss * 16 + kg * 4 + r;
                pc[ss][r] = (s <= t) ? (_Float16)(e[ss][r] * inv) : (_Float16)0.f;
            }
        f32x4 acc = zero;
#pragma unroll
        for (int ss = 0; ss < 4; ++ss)
            acc = MFMA16(vvf[ss], pc[ss], acc, 0, 0, 0);
        f16x4 rt;
#pragma unroll
        for (int r = 0; r < 4; ++r) rt[r] = (_Float16)fmaxf(acc[r], 0.f);
        f32x4 rp = MFMA16(wlf, rt, zero, 0, 0, 0);
        float4 o4; o4.x = rp[0]; o4.y = rp[1]; o4.z = rp[2]; o4.w = rp[3];
        *(float4*)&Rs[h][t][kg * 4] = o4;
    }
    __syncthreads();

    {
        int t = tid >> 2, o0 = (tid & 3) * 4;
        float4 r0 = *(const float4*)&Rs[0][t][o0];
        float4 r1 = *(const float4*)&Rs[1][t][o0];
        float4 r2 = *(const float4*)&Rs[2][t][o0];
        float4 r3 = *(const float4*)&Rs[3][t][o0];
        // residual from X16 (same rounded X the gconv consumed) — contiguous
        f16x4 xv = *(const f16x4*)&X16[(size_t)n * M_ + b * (T_ * DH) + t * DH + o0];
        float y0 = (float)xv[0] + fmaxf(r0.x + r1.x + r2.x + r3.x + bls[o0 + 0], 0.f);
        float y1 = (float)xv[1] + fmaxf(r0.y + r1.y + r2.y + r3.y + bls[o0 + 1], 0.f);
        float y2 = (float)xv[2] + fmaxf(r0.z + r1.z + r2.z + r3.z + bls[o0 + 2], 0.f);
        float y3 = (float)xv[3] + fmaxf(r0.w + r1.w + r2.w + r3.w + bls[o0 + 3], 0.f);
        f16x4 yv16;
        yv16[0] = (_Float16)y0; yv16[1] = (_Float16)y1;
        yv16[2] = (_Float16)y2; yv16[3] = (_Float16)y3;
        // OUTPUT-order store: [b][t][n][c]
        *(f16x4*)&ypre16[(((size_t)(b * T_ + t) * N_) + n) * DH + o0] = yv16;
        float ls = (y0 + y1) + (y2 + y3);
        float lq = (y0 * y0 + y1 * y1) + (y2 * y2 + y3 * y3);
#pragma unroll
        for (int off = 32; off > 0; off >>= 1) { ls += __shfl_down(ls, off); lq += __shfl_down(lq, off); }
        if (l == 0) { lnp[h][0] = ls; lnp[h][1] = lq; }
    }
    __syncthreads();
    if (tid == 0) {
        part[bn * 2]     = (lnp[0][0] + lnp[1][0]) + (lnp[2][0] + lnp[3][0]);
        part[bn * 2 + 1] = (lnp[0][1] + lnp[1][1]) + (lnp[2][1] + lnp[3][1]);
    }
}

// ---------------- K4: LN stats + normalize, block=(b,t) ----------------------
__global__ __launch_bounds__(256) void k_lnapply(const _Float16* __restrict__ y16,
                                                 const float* __restrict__ part,
                                                 const float* __restrict__ gamma,
                                                 const float* __restrict__ beta,
                                                 float* __restrict__ out) {
    __shared__ float gs[N_ * DH];    // 20.8 KB, layout [c][n]
    __shared__ float bsh[N_ * DH];   // 20.8 KB
    __shared__ float ssum[256], ssq[256];
    int blk = blockIdx.x, tid = threadIdx.x;
    int b = blk >> 6, t = blk & 63;
    for (int i = tid; i < N_ * DH; i += 256) {      // i = c*325+n: contiguous runs
        int c = i / N_, n = i - c * N_;
        size_t g = (size_t)(c * T_ + t) * N_ + n;
        gs[i] = gamma[g];
        bsh[i] = beta[g];
    }
    float s = 0.f, q = 0.f;
    for (int i = tid; i < N_; i += 256) {
        s += part[(b * N_ + i) * 2];
        q += part[(b * N_ + i) * 2 + 1];
    }
    ssum[tid] = s; ssq[tid] = q;
    __syncthreads();
    for (int st = 128; st > 0; st >>= 1) {
        if (tid < st) { ssum[tid] += ssum[tid + st]; ssq[tid] += ssq[tid + st]; }
        __syncthreads();
    }
    float mu = ssum[0] / 332800.f;
    float rs = rsqrtf(ssq[0] / 332800.f - mu * mu + 1e-5f);

    float* ob = out + (size_t)(b * T_ + t) * (N_ * DH);
    const _Float16* yb = y16 + (size_t)(b * T_ + t) * (N_ * DH);
    for (int e4 = tid; e4 < (N_ * DH) / 4; e4 += 256) {   // contiguous f16x4 / float4
        f16x4 yv = *(const f16x4*)&yb[e4 * 4];
        int e = e4 * 4;
        int n = e >> 4, c0 = e & 15;
        float4 o;
        o.x = ((float)yv[0] - mu) * rs * gs[(c0 + 0) * N_ + n] + bsh[(c0 + 0) * N_ + n];
        o.y = ((float)yv[1] - mu) * rs * gs[(c0 + 1) * N_ + n] + bsh[(c0 + 1) * N_ + n];
        o.z = ((float)yv[2] - mu) * rs * gs[(c0 + 2) * N_ + n] + bsh[(c0 + 2) * N_ + n];
        o.w = ((float)yv[3] - mu) * rs * gs[(c0 + 3) * N_ + n] + bsh[(c0 + 3) * N_ + n];
        *(float4*)&ob[e] = o;
    }
}

extern "C" void kernel_launch(void* const* d_in, const int* in_sizes, int n_in,
                              void* d_out, int out_size, void* d_ws, size_t ws_size,
                              hipStream_t stream) {
    const float* in   = (const float*)d_in[0];
    const float* adj  = (const float*)d_in[1];
    const float* w_lt = (const float*)d_in[2];
    const float* b_lt = (const float*)d_in[3];
    const float* wq   = (const float*)d_in[4];
    const float* bq   = (const float*)d_in[5];
    const float* wk   = (const float*)d_in[6];
    const float* bk   = (const float*)d_in[7];
    const float* wv   = (const float*)d_in[8];
    const float* bv   = (const float*)d_in[9];
    const float* wls  = (const float*)d_in[10];
    const float* bls  = (const float*)d_in[11];
    const float* gam  = (const float*)d_in[12];
    const float* bet  = (const float*)d_in[13];
    float* out = (float*)d_out;

    float* ws = (float*)d_ws;
    _Float16* S16    = (_Float16*)ws;                              // NP*NP f16
    _Float16* X16    = (_Float16*)(ws + 56576);                    // 1,331,200 f16
    _Float16* lfs16  = (_Float16*)(ws + 56576 + 665600);           // 1,331,200 f16
    _Float16* ypre16 = (_Float16*)(ws + 56576 + 665600 + 665600);  // 1,331,200 f16 [b][t][n][c]
    float* part = ws + 56576 + 665600 + 665600 + 665600;           // 2600

    k_prep<<<126 + 1300, 256, 0, stream>>>(adj, in, w_lt, b_lt, S16, X16);
    k_gconv<<<dim3(32, 21), 256, 0, stream>>>(S16, X16, lfs16);
    k_attn<<<B_ * N_, 256, 0, stream>>>(lfs16, X16, wq, bq, wk, bk, wv, bv, wls, bls, ypre16, part);
    k_lnapply<<<B_ * T_, 256, 0, stream>>>(ypre16, part, gam, bet, out);
}